// Round 7
// baseline (593.461 us; speedup 1.0000x reference)
//
#include <hip/hip_runtime.h>

// ---------------------------------------------------------------------------
// GCN block: 3 x (GCNConv -> ReLU -> global_mean_pool)
// 11 dispatches. ZERO device-scope atomics in the CSR build (R11: 1.6M
// device atomics rate-limit ~18G/s memory-side regardless of structure).
// R13/R16/R17: k_agg is L2-MISS-TRAFFIC bound (199MB fetch @ ~3.5TB/s;
// deeper MLP neutral, quad-edge issue-halving neutral). R17 (this round):
// HALF-SPLIT gather — one dispatch, 2x grid; blocks[0,nb) do features 0..63,
// blocks[nb,2nb) do 64..127. HW dispatches blocks ~in order (2048 resident
// of 25K/half) so the halves run as near-disjoint epochs with a 12.8MB
// gather working set each (vs 25.6MB), raising per-XCD L2 hit rate. One
// gather = 128B = exactly one L2 line. csr is now IMMUTABLE: *dinv[src]
// applied at LDS-stage time every layer (dinv 400KB L2-resident) — no
// write-back, no NORM template, no cross-half race.
//   k_prep:      graph bounds + WbT transpose/cast
//   k_phase1:    blocks[0..782) = layer-1 MFMA GEMM (fp32 x, in-reg bf16
//                cast); blocks[782..978) = LDS histogram over 782 coarse
//                buckets (col>>7), plain writes
//   k_scan1:     1024-chunk exclusive scan over the 153K hist matrix
//   k_scat:      inline LDS scan of chunk sums; LDS-atomic ranks; packed
//                (r|c_local<<17, w) records bucket-contiguous (recs=bufB)
//   k_fin:       per bucket: count + weighted degree in LDS, dinv, ptr,
//                self-loop edge at list head, csr.x = node*16 (uint4-row
//                index), csr.y = w*dinv[c]
//   per layer:   k_agg (wave-per-node-half, 8-edge-wide uint4 gather) ->
//                k_gemm_pool (next-layer GEMM + prev-layer pool fused;
//                final call pool-only, nbGemm=0)
// hist/pre alias csr (dead before k_fin); recs aliases bufB (dead before
// k_agg L1 writes bufB).
// ---------------------------------------------------------------------------

typedef short short8 __attribute__((ext_vector_type(8)));   // 8 bf16 (4 VGPR)
typedef float f32x4  __attribute__((ext_vector_type(4)));   // MFMA C/D

__device__ inline unsigned pack_bf16x2(float a, float b) {
    unsigned ua = __float_as_uint(a);
    ua = (ua + 0x7FFFu + ((ua >> 16) & 1u)) >> 16;       // RNE
    unsigned ub = __float_as_uint(b);
    ub = (ub + 0x7FFFu + ((ub >> 16) & 1u)) >> 16;
    return ua | (ub << 16);
}
__device__ inline ushort bf16_1(float a) {
    unsigned ua = __float_as_uint(a);
    return (ushort)((ua + 0x7FFFu + ((ua >> 16) & 1u)) >> 16);
}
__device__ inline float bf_lo(unsigned u) { return __uint_as_float(u << 16); }
__device__ inline float bf_hi(unsigned u) { return __uint_as_float(u & 0xFFFF0000u); }

// ---- shared device bodies -------------------------------------------------

// One block = 128 rows x 128 cols of hl = H @ W (v_mfma_f32_16x16x32_bf16).
// Wave = 32 rows: 2 m-strips x 8 n-tiles, 64 MFMAs. A-frag 16B/lane
// contiguous (F32IN: 32B fp32 -> in-register bf16 cast). B from WbT[n][k].
// Epilogue via LDS (sOut, 8192 u32) -> coalesced u32 stores.
template <bool F32IN>
__device__ __forceinline__ void gemm_tile(const void* __restrict__ Hin,
                                          const ushort* __restrict__ WbT,
                                          unsigned* __restrict__ O, int M,
                                          int bid, unsigned* sOut) {
    int lane = threadIdx.x & 63;
    int wv = threadIdx.x >> 6;
    int quad = lane >> 4;
    int mrow = lane & 15;
    int m0 = bid * 128 + wv * 32;
    int r0 = m0 + mrow;
    int r1 = r0 + 16;
    int r0c = r0 < M ? r0 : M - 1;             // clamp loads, guard stores
    int r1c = r1 < M ? r1 : M - 1;

    short8 a0[4], a1[4];
    if (F32IN) {
        const float* Hf = (const float*)Hin;
#pragma unroll
        for (int s = 0; s < 4; s++) {          // k-step s covers k in [32s,32s+32)
            const float4* p0 = (const float4*)(Hf + (size_t)r0c * 128 + s * 32 + quad * 8);
            const float4* p1 = (const float4*)(Hf + (size_t)r1c * 128 + s * 32 + quad * 8);
            float4 f0 = p0[0], f1 = p0[1];
            float4 g0 = p1[0], g1 = p1[1];
            union { short8 s8; unsigned u[4]; } t0, t1;
            t0.u[0] = pack_bf16x2(f0.x, f0.y); t0.u[1] = pack_bf16x2(f0.z, f0.w);
            t0.u[2] = pack_bf16x2(f1.x, f1.y); t0.u[3] = pack_bf16x2(f1.z, f1.w);
            t1.u[0] = pack_bf16x2(g0.x, g0.y); t1.u[1] = pack_bf16x2(g0.z, g0.w);
            t1.u[2] = pack_bf16x2(g1.x, g1.y); t1.u[3] = pack_bf16x2(g1.z, g1.w);
            a0[s] = t0.s8; a1[s] = t1.s8;
        }
    } else {
        const unsigned* Hb = (const unsigned*)Hin;
#pragma unroll
        for (int s = 0; s < 4; s++) {
            a0[s] = *(const short8*)(Hb + (size_t)r0c * 64 + s * 16 + quad * 4);
            a1[s] = *(const short8*)(Hb + (size_t)r1c * 64 + s * 16 + quad * 4);
        }
    }
    f32x4 acc0[8], acc1[8];
#pragma unroll
    for (int t = 0; t < 8; t++) {
        acc0[t] = (f32x4){0.f, 0.f, 0.f, 0.f};
        acc1[t] = (f32x4){0.f, 0.f, 0.f, 0.f};
    }
#pragma unroll
    for (int s = 0; s < 4; s++) {
#pragma unroll
        for (int t = 0; t < 8; t++) {
            short8 b = *(const short8*)(WbT + (t * 16 + mrow) * 128 + s * 32 + quad * 8);
            acc0[t] = __builtin_amdgcn_mfma_f32_16x16x32_bf16(a0[s], b, acc0[t], 0, 0, 0);
            acc1[t] = __builtin_amdgcn_mfma_f32_16x16x32_bf16(a1[s], b, acc1[t], 0, 0, 0);
        }
    }
    // C/D layout: col = lane&15, row = quad*4 + reg.
    ushort* so = (ushort*)(sOut + wv * 32 * 64);
#pragma unroll
    for (int t = 0; t < 8; t++) {
#pragma unroll
        for (int r = 0; r < 4; r++) {
            int lr = quad * 4 + r;
            int c = t * 16 + mrow;
            so[lr * 128 + c] = bf16_1(acc0[t][r]);
            so[(lr + 16) * 128 + c] = bf16_1(acc1[t][r]);
        }
    }
    __syncthreads();
    const unsigned* si = sOut + wv * 32 * 64;
#pragma unroll 8
    for (int r = 0; r < 32; r++) {
        int row = m0 + r;
        if (row < M) O[(size_t)row * 64 + lane] = si[r * 64 + lane];
    }
}

// One block per graph: stream the sorted node segment, 4 waves stride it,
// LDS-combine (part = 512 floats), divide by count, write. No atomics.
__device__ __forceinline__ void pool_tile(const unsigned* __restrict__ HB,
                                          const int* __restrict__ gb,
                                          float* __restrict__ outp, int g,
                                          float* part) {
    int lane = threadIdx.x & 63, w = threadIdx.x >> 6;
    int s = gb[g], e = gb[g + 1];
    float ax = 0.f, ay = 0.f;
    for (int i = s + w; i < e; i += 4) {
        unsigned u = HB[(size_t)i * 64 + lane];
        ax += bf_lo(u); ay += bf_hi(u);
    }
    part[w * 128 + lane * 2] = ax;
    part[w * 128 + lane * 2 + 1] = ay;
    __syncthreads();
    if (threadIdx.x < 128) {
        float sum = part[threadIdx.x] + part[128 + threadIdx.x]
                  + part[256 + threadIdx.x] + part[384 + threadIdx.x];
        float c = (float)(e - s);
        outp[g * 128 + threadIdx.x] = sum / fmaxf(c, 1.0f);
    }
}

// ---- kernels --------------------------------------------------------------

// Pre-pass: graph bounds + W transpose+cast.
__global__ void k_prep(const int* __restrict__ batch, int* __restrict__ gb,
                       int G, int N,
                       const float* __restrict__ W0, const float* __restrict__ W1,
                       const float* __restrict__ W2, ushort* __restrict__ WbT) {
    int id = blockIdx.x * blockDim.x + threadIdx.x;
    if (id <= G) {
        int lo = 0, hi = N;
        while (lo < hi) { int mid = (lo + hi) >> 1; if (batch[mid] < id) lo = mid + 1; else hi = mid; }
        gb[id] = lo;
    }
    if (id < 3 * 16384) {
        int l = id >> 14;
        const float* W = (l == 0) ? W0 : ((l == 1) ? W1 : W2);
        int id2 = id & 16383;
        int n = id2 & 127, k = id2 >> 7;
        WbT[l * 16384 + n * 128 + k] = bf16_1(W[k * 128 + n]);
    }
}

// Heterogeneous: blocks[0..nbGemm) = layer-1 GEMM (fp32 x, in-reg bf16 cast);
// blocks[nbGemm..nbGemm+nbCount) = LDS histogram over nbGemm (=nbkt) coarse
// buckets (col>>7), 8192 edges/block, plain hist writes. NO global atomics.
__global__ __launch_bounds__(256) void k_phase1(const int* __restrict__ ei,
                                                int* __restrict__ hist, int E,
                                                const float* __restrict__ x,
                                                const ushort* __restrict__ WbT,
                                                unsigned* __restrict__ O, int M,
                                                int nbGemm, int nbCount) {
    __shared__ unsigned sBuf[8192];            // 32 KB (gemm epilogue / hist)
    if (blockIdx.x < nbGemm) {
        gemm_tile<true>(x, WbT, O, M, blockIdx.x, sBuf);
        return;
    }
    int blk = blockIdx.x - nbGemm;
    unsigned* hcnt = sBuf;                     // nbkt (<=784) counters
    int t = threadIdx.x;
    for (int i = t; i < nbGemm; i += 256) hcnt[i] = 0;
    __syncthreads();
    int base = blk * 8192;
    for (int i = t; i < 8192; i += 256) {
        int e = base + i;
        if (e < E) atomicAdd(&hcnt[(unsigned)ei[E + e] >> 7], 1u);  // LDS atomic
    }
    __syncthreads();
    for (int b = t; b < nbGemm; b += 256)      // bucket-major layout
        hist[b * nbCount + blk] = (int)hcnt[b];
}

// 1024-chunk exclusive scan: pre[i] = chunk-local exclusive prefix,
// bsum[chunk] = chunk total. n = nbkt*nbCount (~153K).
__global__ __launch_bounds__(1024) void k_scan1(const int* __restrict__ cnt,
                                                int* __restrict__ pre,
                                                int* __restrict__ bsum, int n) {
    __shared__ int wsum[16];
    int t = threadIdx.x, lane = t & 63, w = t >> 6;
    int i = blockIdx.x * 1024 + t;
    int v = (i < n) ? cnt[i] : 0;
    int x = v;
#pragma unroll
    for (int off = 1; off < 64; off <<= 1) {
        int y = __shfl_up(x, off, 64);
        if (lane >= off) x += y;
    }
    if (lane == 63) wsum[w] = x;
    __syncthreads();
    int woff = 0, tot = 0;
#pragma unroll
    for (int q = 0; q < 16; q++) { int s = wsum[q]; if (q < w) woff += s; tot += s; }
    if (i < n) pre[i] = woff + x - v;
    if (t == 0) bsum[blockIdx.x] = tot;
}

// Pass C: inline LDS scan of the (<=256) chunk sums; per-bucket bases into
// LDS; per-edge rank via LDS atomic; write packed records into bucket-
// contiguous regions. Block 0 also emits bucketStart[].
__global__ __launch_bounds__(256) void k_scat(const int* __restrict__ ei,
                                              const float* __restrict__ ew,
                                              const int* __restrict__ pre,
                                              const int* __restrict__ bsumRaw,
                                              int* __restrict__ bucketStart,
                                              int2* __restrict__ recs,
                                              int E, int nbkt, int nbCount,
                                              int nbScan) {
    __shared__ int sRaw[256];
    __shared__ int sPre[256];
    __shared__ int sWt[4];
    __shared__ int sBase[784];
    __shared__ unsigned rk[784];
    int t = threadIdx.x;
    sRaw[t] = (t < nbScan) ? bsumRaw[t] : 0;
    for (int b = t; b < nbkt; b += 256) rk[b] = 0;
    __syncthreads();
    int lane = t & 63, w2 = t >> 6;
    int v = sRaw[t];
    int x = v;
#pragma unroll
    for (int off = 1; off < 64; off <<= 1) {
        int y = __shfl_up(x, off, 64);
        if (lane >= off) x += y;
    }
    if (lane == 63) sWt[w2] = x;
    __syncthreads();
    int base = 0;
#pragma unroll
    for (int q = 0; q < 4; q++) { if (q < w2) base += sWt[q]; }
    sPre[t] = base + x - v;                    // exclusive prefix of chunk sums
    __syncthreads();
    int blk = blockIdx.x;
    for (int b = t; b < nbkt; b += 256) {
        int f = b * nbCount + blk;
        sBase[b] = pre[f] + sPre[f >> 10];     // this block's base in bucket b
    }
    if (blk == 0) {
        for (int b = t; b <= nbkt; b += 256) {
            if (b == nbkt) bucketStart[b] = E;
            else { int f = b * nbCount; bucketStart[b] = pre[f] + sPre[f >> 10]; }
        }
    }
    __syncthreads();
    int e0 = blk * 8192;
    for (int i = t; i < 8192; i += 256) {
        int e = e0 + i;
        if (e < E) {
            int r = ei[e];
            int c = ei[E + e];
            float w = ew[e];
            int b = (unsigned)c >> 7;
            unsigned rank = atomicAdd(&rk[b], 1u);      // LDS atomic
            int2 rec; rec.x = r | ((c & 127) << 17); rec.y = __float_as_int(w);
            recs[sBase[b] + (int)rank] = rec;
        }
    }
}

// Pass D: one block per bucket (128 nodes). Count + weighted degree in LDS;
// dinv = rsqrt(1 + wdeg); SELF-LOOP edge at each node's list head
// (y = dinv[c]; k_agg's stage-time *dinv[src] makes it dinv^2); ptr includes
// the self slot; in-bucket scatter with csr.y = w * dinv[c]. csr.x is stored
// PRE-SCALED as node*16 (uint4-row index). csr is IMMUTABLE afterwards.
__global__ __launch_bounds__(256) void k_fin(const int2* __restrict__ recs,
                                             const int* __restrict__ bucketStart,
                                             int2* __restrict__ csr,
                                             int* __restrict__ ptrv,
                                             float* __restrict__ dinv,
                                             int N, int nbkt) {
    __shared__ unsigned scnt[128];
    __shared__ float swdeg[128];
    __shared__ float sdinv[128];
    __shared__ unsigned sTot0;
    int t = threadIdx.x;
    int b = blockIdx.x;
    int e0 = bucketStart[b], e1 = bucketStart[b + 1];
    int FB = e0 + b * 128;                     // final base incl. prior selfs
    if (t < 128) { scnt[t] = 0u; swdeg[t] = 0.f; }
    __syncthreads();
    for (int i = e0 + t; i < e1; i += 256) {
        int2 rec = recs[i];
        int cl = (rec.x >> 17) & 127;
        atomicAdd(&scnt[cl], 1u);                       // LDS atomic
        atomicAdd(&swdeg[cl], __int_as_float(rec.y));   // LDS f32 atomic
    }
    __syncthreads();
    unsigned myc = (t < 128) ? scnt[t] : 0u;
    int lane = t & 63, wv = t >> 6;
    unsigned inc = myc;
#pragma unroll
    for (int off = 1; off < 64; off <<= 1) {
        unsigned y = __shfl_up(inc, off, 64);
        if (lane >= off) inc += y;
    }
    if (t == 63) sTot0 = inc;                  // wave-0 total
    __syncthreads();
    unsigned excl = inc - myc + ((wv == 1) ? sTot0 : 0u);
    if (t < 128) {
        float dv = rsqrtf(1.0f + swdeg[t]);
        sdinv[t] = dv;
        scnt[t] = excl + (unsigned)t + 1u;     // scatter cursor (rel. to FB)
        int node = b * 128 + t;
        int start = FB + (int)excl + t;
        if (node < N) {
            ptrv[node] = start;
            dinv[node] = dv;
            int2 sv; sv.x = node << 4;         // self: w=1*dinv[c], scaled idx
            sv.y = __float_as_int(dv);
            csr[start] = sv;
        }
    }
    if (b == nbkt - 1 && t == 0) ptrv[N] = e1 + N;  // = E + N
    __syncthreads();
    for (int i = e0 + t; i < e1; i += 256) {
        int2 rec = recs[i];
        int cl = (rec.x >> 17) & 127;
        int r = rec.x & 131071;
        unsigned rank = atomicAdd(&scnt[cl], 1u);       // LDS atomic
        float y = __int_as_float(rec.y) * sdinv[cl];
        int2 mv; mv.x = r << 4; mv.y = __float_as_int(y);
        csr[FB + (int)rank] = mv;
    }
}

// Half-split aggregate (R17). Grid = 2*nbHalf blocks; blocks [0,nbHalf) do
// features 0..63 (half 0), [nbHalf,2*nbHalf) do 64..127 — near-disjoint
// temporal epochs shrink the gather working set to 12.8MB each. One wave
// per (node, half): lane = (grp = lane>>3 in 0..7 edges, q = lane&7 uint4).
// One gather = uint4 at HL4[src*16 + half*8 + q] (128B/edge-half = 1 L2
// line). *dinv[src] applied at stage time (dinv L2-resident); csr immutable.
__global__ __launch_bounds__(256) void k_agg(const unsigned* __restrict__ HL,
                                             const int* __restrict__ ptr,
                                             const int2* __restrict__ csr,
                                             const float* __restrict__ dinv,
                                             const float* __restrict__ bias,
                                             unsigned* __restrict__ Hout, int M,
                                             int nbHalf) {
    __shared__ int2 sM[4 * 64];
    int half = blockIdx.x >= nbHalf ? 1 : 0;
    int bid = blockIdx.x - half * nbHalf;
    int node = (int)(((size_t)bid * blockDim.x + threadIdx.x) >> 6);
    if (node >= M) return;
    int lane = threadIdx.x & 63;
    int grp = lane >> 3;                  // edge subgroup 0..7
    int q = lane & 7;                     // uint4 index within the half-row
    int hb = half * 8 + q;                // uint4 offset within the full row
    int2* mbase = &sM[(threadIdx.x >> 6) * 64];
    int e0 = ptr[node], e1 = ptr[node + 1];
    int deg = e1 - e0;                    // includes self edge
    int nbv = deg < 64 ? deg : 64;
    if (lane < nbv) {
        int2 m = csr[e0 + lane];          // one coalesced load
        m.y = __float_as_int(__int_as_float(m.y) * dinv[m.x >> 4]);
        mbase[lane] = m;
    }
    const uint4* HL4 = (const uint4*)HL;  // row = 16 uint4
    float a0 = 0.f, a1 = 0.f, a2 = 0.f, a3 = 0.f;
    float a4 = 0.f, a5 = 0.f, a6 = 0.f, a7 = 0.f;
    int j = grp;
    for (; j + 16 <= nbv; j += 16) {      // 2 gathers in flight per lane
        int2 m0 = mbase[j], m1 = mbase[j + 8];
        uint4 u0 = HL4[(unsigned)(m0.x + hb)];
        uint4 u1 = HL4[(unsigned)(m1.x + hb)];
        float n0 = __int_as_float(m0.y);
        float n1 = __int_as_float(m1.y);
        a0 += n0 * bf_lo(u0.x); a1 += n0 * bf_hi(u0.x);
        a2 += n0 * bf_lo(u0.y); a3 += n0 * bf_hi(u0.y);
        a4 += n0 * bf_lo(u0.z); a5 += n0 * bf_hi(u0.z);
        a6 += n0 * bf_lo(u0.w); a7 += n0 * bf_hi(u0.w);
        a0 += n1 * bf_lo(u1.x); a1 += n1 * bf_hi(u1.x);
        a2 += n1 * bf_lo(u1.y); a3 += n1 * bf_hi(u1.y);
        a4 += n1 * bf_lo(u1.z); a5 += n1 * bf_hi(u1.z);
        a6 += n1 * bf_lo(u1.w); a7 += n1 * bf_hi(u1.w);
    }
    for (; j < nbv; j += 8) {             // remainder
        int2 m = mbase[j];
        uint4 u = HL4[(unsigned)(m.x + hb)];
        float nv = __int_as_float(m.y);
        a0 += nv * bf_lo(u.x); a1 += nv * bf_hi(u.x);
        a2 += nv * bf_lo(u.y); a3 += nv * bf_hi(u.y);
        a4 += nv * bf_lo(u.z); a5 += nv * bf_hi(u.z);
        a6 += nv * bf_lo(u.w); a7 += nv * bf_hi(u.w);
    }
    for (int e = e0 + 64 + grp; e < e1; e += 8) {  // rare high-degree tail
        int2 m = csr[e];
        m.y = __float_as_int(__int_as_float(m.y) * dinv[m.x >> 4]);
        uint4 u = HL4[(unsigned)(m.x + hb)];
        float nv = __int_as_float(m.y);
        a0 += nv * bf_lo(u.x); a1 += nv * bf_hi(u.x);
        a2 += nv * bf_lo(u.y); a3 += nv * bf_hi(u.y);
        a4 += nv * bf_lo(u.z); a5 += nv * bf_hi(u.z);
        a6 += nv * bf_lo(u.w); a7 += nv * bf_hi(u.w);
    }
    // combine the 8 edge subgroups: xor 32, 16, 8
    a0 += __shfl_xor(a0, 32, 64); a1 += __shfl_xor(a1, 32, 64);
    a2 += __shfl_xor(a2, 32, 64); a3 += __shfl_xor(a3, 32, 64);
    a4 += __shfl_xor(a4, 32, 64); a5 += __shfl_xor(a5, 32, 64);
    a6 += __shfl_xor(a6, 32, 64); a7 += __shfl_xor(a7, 32, 64);
    a0 += __shfl_xor(a0, 16, 64); a1 += __shfl_xor(a1, 16, 64);
    a2 += __shfl_xor(a2, 16, 64); a3 += __shfl_xor(a3, 16, 64);
    a4 += __shfl_xor(a4, 16, 64); a5 += __shfl_xor(a5, 16, 64);
    a6 += __shfl_xor(a6, 16, 64); a7 += __shfl_xor(a7, 16, 64);
    a0 += __shfl_xor(a0, 8, 64);  a1 += __shfl_xor(a1, 8, 64);
    a2 += __shfl_xor(a2, 8, 64);  a3 += __shfl_xor(a3, 8, 64);
    a4 += __shfl_xor(a4, 8, 64);  a5 += __shfl_xor(a5, 8, 64);
    a6 += __shfl_xor(a6, 8, 64);  a7 += __shfl_xor(a7, 8, 64);
    if (grp == 0) {
        const float4* b4 = (const float4*)bias;
        float4 bA = b4[2 * hb], bB = b4[2 * hb + 1];
        float r0 = fmaxf(a0 + bA.x, 0.f);
        float r1 = fmaxf(a1 + bA.y, 0.f);
        float r2 = fmaxf(a2 + bA.z, 0.f);
        float r3 = fmaxf(a3 + bA.w, 0.f);
        float r4 = fmaxf(a4 + bB.x, 0.f);
        float r5 = fmaxf(a5 + bB.y, 0.f);
        float r6 = fmaxf(a6 + bB.z, 0.f);
        float r7 = fmaxf(a7 + bB.w, 0.f);
        uint4 pv;
        pv.x = pack_bf16x2(r0, r1);
        pv.y = pack_bf16x2(r2, r3);
        pv.z = pack_bf16x2(r4, r5);
        pv.w = pack_bf16x2(r6, r7);
        ((uint4*)(Hout + (size_t)node * 64))[hb] = pv;
    }
}

// Heterogeneous: blocks[0..nbGemm) = next-layer GEMM reading Hb;
// blocks[nbGemm..nbGemm+G) = pool of the SAME Hb into outp (both depend only
// on the preceding agg). nbGemm=0 -> pool-only (final layer).
__global__ __launch_bounds__(256) void k_gemm_pool(const unsigned* __restrict__ Hb,
                                                   const ushort* __restrict__ WbT,
                                                   unsigned* __restrict__ O, int M,
                                                   const int* __restrict__ gb,
                                                   float* __restrict__ outp,
                                                   int nbGemm) {
    __shared__ unsigned sBuf[8192];            // gemm epilogue / pool partials
    if (blockIdx.x < nbGemm) {
        gemm_tile<false>(Hb, WbT, O, M, blockIdx.x, sBuf);
        return;
    }
    pool_tile(Hb, gb, outp, blockIdx.x - nbGemm, (float*)sBuf);
}

extern "C" void kernel_launch(void* const* d_in, const int* in_sizes, int n_in,
                              void* d_out, int out_size, void* d_ws, size_t ws_size,
                              hipStream_t stream) {
    const float* x     = (const float*)d_in[0];
    const int*   ei    = (const int*)d_in[1];
    const float* ew    = (const float*)d_in[2];
    const int*   batch = (const int*)d_in[3];
    const float* Wt[3] = {(const float*)d_in[4], (const float*)d_in[6], (const float*)d_in[8]};
    const float* bt[3] = {(const float*)d_in[5], (const float*)d_in[7], (const float*)d_in[9]};
    float* out = (float*)d_out;

    const int D = 128;
    const int N = in_sizes[0] / D;       // 100000
    const int E = in_sizes[2];           // 1600000
    const int G = out_size / (3 * D);    // 256

    // workspace carve-up (256 B aligned)
    char* p = (char*)d_ws;
    auto alloc = [&](size_t bytes) {
        void* r = (void*)p;
        p += (bytes + 255) & ~(size_t)255;
        return r;
    };
    int nbkt    = (N + 127) / 128;              // 782 coarse buckets (== nbGemm)
    int nbCount = (E + 8191) / 8192;            // 196 histogram blocks
    int F       = nbkt * nbCount;               // 153272 scan elements
    int nbScan  = (F + 1023) / 1024;            // 150 (<=256 for inline scan)

    int*      ptr    = (int*)alloc((size_t)(N + 1) * 4);
    int*      bsum   = (int*)alloc((size_t)256 * 4);
    int*      gb     = (int*)alloc((size_t)(G + 1) * 4);
    int*      bstart = (int*)alloc((size_t)(nbkt + 1) * 4);
    float*    dinv   = (float*)alloc((size_t)N * 4);
    ushort*   WbT    = (ushort*)alloc((size_t)3 * 16384 * 2);
    int2*     csr    = (int2*)alloc((size_t)(E + N) * 8);     // incl. selfs
    unsigned* bufA   = (unsigned*)alloc((size_t)N * 64 * 4);  // hl ping
    unsigned* bufB   = (unsigned*)alloc((size_t)N * 64 * 4);  // h / hl pong
    // aliases: hist+pre live only before k_fin writes csr; recs dead before
    // k_agg L1 writes bufB.
    int*  hist = (int*)csr;                    // F ints (613 KB)
    int*  pre  = hist + F;                     // F ints
    int2* recs = (int2*)bufB;                  // E int2 (12.8 MB)

    int nbGemm = nbkt;                          // 782 gemm blocks
    int nbHalf = (N + 3) / 4;                   // agg blocks per feature half
    int prepWork = 3 * 16384;

    k_prep<<<(prepWork + 255) / 256, 256, 0, stream>>>(batch, gb, G, N,
                                                       Wt[0], Wt[1], Wt[2], WbT);
    // layer-1 GEMM fused with the histogram pass (independent inputs)
    k_phase1<<<nbGemm + nbCount, 256, 0, stream>>>(ei, hist, E, x, WbT,
                                                   bufA, N, nbGemm, nbCount);
    k_scan1<<<nbScan, 1024, 0, stream>>>(hist, pre, bsum, F);
    k_scat<<<nbCount, 256, 0, stream>>>(ei, ew, pre, bsum, bstart, recs,
                                        E, nbkt, nbCount, nbScan);
    k_fin<<<nbkt, 256, 0, stream>>>(recs, bstart, csr, ptr, dinv, N, nbkt);

    // half-split aggregate, then fused (gemm_{l+1} + pool_l), final pool-only.
    k_agg<<<2 * nbHalf, 256, 0, stream>>>(bufA, ptr, csr, dinv, bt[0],
                                          bufB, N, nbHalf);
    k_gemm_pool<<<nbGemm + G, 256, 0, stream>>>(bufB, WbT + 16384, bufA, N,
                                                gb, out + 0 * (size_t)G * D, nbGemm);
    k_agg<<<2 * nbHalf, 256, 0, stream>>>(bufA, ptr, csr, dinv, bt[1],
                                          bufB, N, nbHalf);
    k_gemm_pool<<<nbGemm + G, 256, 0, stream>>>(bufB, WbT + 2 * 16384, bufA, N,
                                                gb, out + 1 * (size_t)G * D, nbGemm);
    k_agg<<<2 * nbHalf, 256, 0, stream>>>(bufA, ptr, csr, dinv, bt[2],
                                          bufB, N, nbHalf);
    k_gemm_pool<<<G, 256, 0, stream>>>(bufB, WbT, nullptr, 0,
                                       gb, out + 2 * (size_t)G * D, 0);
}

// Round 8
// 498.613 us; speedup vs baseline: 1.1902x; 1.1902x over previous
//
#include <hip/hip_runtime.h>

// ---------------------------------------------------------------------------
// GCN block: 3 x (GCNConv -> ReLU -> global_mean_pool)
// 10 dispatches. ZERO device-scope atomics in the CSR build (R11: 1.6M
// device atomics rate-limit ~18G/s memory-side regardless of structure).
// k_agg is at its structural roofline (R13/R16/R17: ~3.5TB/s L2-miss service
// on random 256B gathers; MLP depth, issue width, VALU count, working-set
// half-split all neutral-or-negative) — R6 quad-edge form kept verbatim.
// R18 (this round): schedule surgery only.
//   k_hist_prep: blocks[0..196) = LDS histogram over 782 coarse buckets
//                (col>>7), plain writes; blocks[196..389) = WbT transpose/
//                cast x3 + gb binary search (consumed only in later
//                dispatches — no same-dispatch ordering needed).
//   k_scan1:     1024-chunk exclusive scan over the 153K hist matrix
//   k_scat_gemm: blocks[0..782) = layer-1 MFMA GEMM (fp32 x, in-reg bf16
//                cast; WbT1 ready since dispatch 1) OVERLAPPED with
//                blocks[782..978) = scat (inline LDS scan of chunk sums;
//                LDS-atomic ranks; packed (r|c_local<<17, w) records
//                bucket-contiguous, recs=bufB). GEMM writes bufA; disjoint.
//   k_fin:       per bucket: count + weighted degree in LDS, dinv, ptr,
//                self-loop edge at list head, csr.x = node*16 (uint4-row
//                index), csr.y = w*dinv[c]
//   per layer:   k_agg<NORM> (wave-per-node quad-edge uint4 gather; NORM on
//                layer 1: csr.y *= dinv[src], written back, race-free) ->
//                k_gemm_pool (next-layer GEMM + prev-layer pool fused;
//                final call pool-only, nbGemm=0)
// hist/pre alias csr (dead before k_fin); recs aliases bufB (dead before
// k_agg L1 writes bufB).
// ---------------------------------------------------------------------------

typedef short short8 __attribute__((ext_vector_type(8)));   // 8 bf16 (4 VGPR)
typedef float f32x4  __attribute__((ext_vector_type(4)));   // MFMA C/D

__device__ inline unsigned pack_bf16x2(float a, float b) {
    unsigned ua = __float_as_uint(a);
    ua = (ua + 0x7FFFu + ((ua >> 16) & 1u)) >> 16;       // RNE
    unsigned ub = __float_as_uint(b);
    ub = (ub + 0x7FFFu + ((ub >> 16) & 1u)) >> 16;
    return ua | (ub << 16);
}
__device__ inline ushort bf16_1(float a) {
    unsigned ua = __float_as_uint(a);
    return (ushort)((ua + 0x7FFFu + ((ua >> 16) & 1u)) >> 16);
}
__device__ inline float bf_lo(unsigned u) { return __uint_as_float(u << 16); }
__device__ inline float bf_hi(unsigned u) { return __uint_as_float(u & 0xFFFF0000u); }

// ---- shared device bodies -------------------------------------------------

// One block = 128 rows x 128 cols of hl = H @ W (v_mfma_f32_16x16x32_bf16).
// Wave = 32 rows: 2 m-strips x 8 n-tiles, 64 MFMAs. A-frag 16B/lane
// contiguous (F32IN: 32B fp32 -> in-register bf16 cast). B from WbT[n][k].
// Epilogue via LDS (sOut, 8192 u32) -> coalesced u32 stores.
template <bool F32IN>
__device__ __forceinline__ void gemm_tile(const void* __restrict__ Hin,
                                          const ushort* __restrict__ WbT,
                                          unsigned* __restrict__ O, int M,
                                          int bid, unsigned* sOut) {
    int lane = threadIdx.x & 63;
    int wv = threadIdx.x >> 6;
    int quad = lane >> 4;
    int mrow = lane & 15;
    int m0 = bid * 128 + wv * 32;
    int r0 = m0 + mrow;
    int r1 = r0 + 16;
    int r0c = r0 < M ? r0 : M - 1;             // clamp loads, guard stores
    int r1c = r1 < M ? r1 : M - 1;

    short8 a0[4], a1[4];
    if (F32IN) {
        const float* Hf = (const float*)Hin;
#pragma unroll
        for (int s = 0; s < 4; s++) {          // k-step s covers k in [32s,32s+32)
            const float4* p0 = (const float4*)(Hf + (size_t)r0c * 128 + s * 32 + quad * 8);
            const float4* p1 = (const float4*)(Hf + (size_t)r1c * 128 + s * 32 + quad * 8);
            float4 f0 = p0[0], f1 = p0[1];
            float4 g0 = p1[0], g1 = p1[1];
            union { short8 s8; unsigned u[4]; } t0, t1;
            t0.u[0] = pack_bf16x2(f0.x, f0.y); t0.u[1] = pack_bf16x2(f0.z, f0.w);
            t0.u[2] = pack_bf16x2(f1.x, f1.y); t0.u[3] = pack_bf16x2(f1.z, f1.w);
            t1.u[0] = pack_bf16x2(g0.x, g0.y); t1.u[1] = pack_bf16x2(g0.z, g0.w);
            t1.u[2] = pack_bf16x2(g1.x, g1.y); t1.u[3] = pack_bf16x2(g1.z, g1.w);
            a0[s] = t0.s8; a1[s] = t1.s8;
        }
    } else {
        const unsigned* Hb = (const unsigned*)Hin;
#pragma unroll
        for (int s = 0; s < 4; s++) {
            a0[s] = *(const short8*)(Hb + (size_t)r0c * 64 + s * 16 + quad * 4);
            a1[s] = *(const short8*)(Hb + (size_t)r1c * 64 + s * 16 + quad * 4);
        }
    }
    f32x4 acc0[8], acc1[8];
#pragma unroll
    for (int t = 0; t < 8; t++) {
        acc0[t] = (f32x4){0.f, 0.f, 0.f, 0.f};
        acc1[t] = (f32x4){0.f, 0.f, 0.f, 0.f};
    }
#pragma unroll
    for (int s = 0; s < 4; s++) {
#pragma unroll
        for (int t = 0; t < 8; t++) {
            short8 b = *(const short8*)(WbT + (t * 16 + mrow) * 128 + s * 32 + quad * 8);
            acc0[t] = __builtin_amdgcn_mfma_f32_16x16x32_bf16(a0[s], b, acc0[t], 0, 0, 0);
            acc1[t] = __builtin_amdgcn_mfma_f32_16x16x32_bf16(a1[s], b, acc1[t], 0, 0, 0);
        }
    }
    // C/D layout: col = lane&15, row = quad*4 + reg.
    ushort* so = (ushort*)(sOut + wv * 32 * 64);
#pragma unroll
    for (int t = 0; t < 8; t++) {
#pragma unroll
        for (int r = 0; r < 4; r++) {
            int lr = quad * 4 + r;
            int c = t * 16 + mrow;
            so[lr * 128 + c] = bf16_1(acc0[t][r]);
            so[(lr + 16) * 128 + c] = bf16_1(acc1[t][r]);
        }
    }
    __syncthreads();
    const unsigned* si = sOut + wv * 32 * 64;
#pragma unroll 8
    for (int r = 0; r < 32; r++) {
        int row = m0 + r;
        if (row < M) O[(size_t)row * 64 + lane] = si[r * 64 + lane];
    }
}

// One block per graph: stream the sorted node segment, 4 waves stride it,
// LDS-combine (part = 512 floats), divide by count, write. No atomics.
__device__ __forceinline__ void pool_tile(const unsigned* __restrict__ HB,
                                          const int* __restrict__ gb,
                                          float* __restrict__ outp, int g,
                                          float* part) {
    int lane = threadIdx.x & 63, w = threadIdx.x >> 6;
    int s = gb[g], e = gb[g + 1];
    float ax = 0.f, ay = 0.f;
    for (int i = s + w; i < e; i += 4) {
        unsigned u = HB[(size_t)i * 64 + lane];
        ax += bf_lo(u); ay += bf_hi(u);
    }
    part[w * 128 + lane * 2] = ax;
    part[w * 128 + lane * 2 + 1] = ay;
    __syncthreads();
    if (threadIdx.x < 128) {
        float sum = part[threadIdx.x] + part[128 + threadIdx.x]
                  + part[256 + threadIdx.x] + part[384 + threadIdx.x];
        float c = (float)(e - s);
        outp[g * 128 + threadIdx.x] = sum / fmaxf(c, 1.0f);
    }
}

// ---- kernels --------------------------------------------------------------

// Heterogeneous: blocks[0..nbCount) = LDS histogram over nbkt coarse buckets
// (col>>7), 8192 edges/block, plain hist writes; blocks[nbCount..) = prep
// work (WbT transpose/cast x3 + gb binary search) consumed only by LATER
// dispatches (scat_gemm / gemm_pool) — no same-dispatch ordering needed.
__global__ __launch_bounds__(256) void k_hist_prep(const int* __restrict__ ei,
                                                   int* __restrict__ hist, int E,
                                                   int nbkt, int nbCount,
                                                   const int* __restrict__ batch,
                                                   int* __restrict__ gb, int G, int N,
                                                   const float* __restrict__ W0,
                                                   const float* __restrict__ W1,
                                                   const float* __restrict__ W2,
                                                   ushort* __restrict__ WbT) {
    __shared__ unsigned hcnt[8192];            // 32 KB (hist counters)
    int t = threadIdx.x;
    if (blockIdx.x >= nbCount) {               // prep blocks
        int id = (blockIdx.x - nbCount) * 256 + t;
        if (id <= G) {
            int lo = 0, hi = N;
            while (lo < hi) { int mid = (lo + hi) >> 1; if (batch[mid] < id) lo = mid + 1; else hi = mid; }
            gb[id] = lo;
        }
        if (id < 3 * 16384) {
            int l = id >> 14;
            const float* W = (l == 0) ? W0 : ((l == 1) ? W1 : W2);
            int id2 = id & 16383;
            int n = id2 & 127, k = id2 >> 7;
            WbT[l * 16384 + n * 128 + k] = bf16_1(W[k * 128 + n]);
        }
        return;
    }
    int blk = blockIdx.x;
    for (int i = t; i < nbkt; i += 256) hcnt[i] = 0;
    __syncthreads();
    int base = blk * 8192;
    for (int i = t; i < 8192; i += 256) {
        int e = base + i;
        if (e < E) atomicAdd(&hcnt[(unsigned)ei[E + e] >> 7], 1u);  // LDS atomic
    }
    __syncthreads();
    for (int b = t; b < nbkt; b += 256)        // bucket-major layout
        hist[b * nbCount + blk] = (int)hcnt[b];
}

// 1024-chunk exclusive scan: pre[i] = chunk-local exclusive prefix,
// bsum[chunk] = chunk total. n = nbkt*nbCount (~153K).
__global__ __launch_bounds__(1024) void k_scan1(const int* __restrict__ cnt,
                                                int* __restrict__ pre,
                                                int* __restrict__ bsum, int n) {
    __shared__ int wsum[16];
    int t = threadIdx.x, lane = t & 63, w = t >> 6;
    int i = blockIdx.x * 1024 + t;
    int v = (i < n) ? cnt[i] : 0;
    int x = v;
#pragma unroll
    for (int off = 1; off < 64; off <<= 1) {
        int y = __shfl_up(x, off, 64);
        if (lane >= off) x += y;
    }
    if (lane == 63) wsum[w] = x;
    __syncthreads();
    int woff = 0, tot = 0;
#pragma unroll
    for (int q = 0; q < 16; q++) { int s = wsum[q]; if (q < w) woff += s; tot += s; }
    if (i < n) pre[i] = woff + x - v;
    if (t == 0) bsum[blockIdx.x] = tot;
}

// Heterogeneous: blocks[0..nbGemm) = layer-1 GEMM (fp32 x, in-reg bf16 cast;
// WbT1 produced by k_hist_prep, one dispatch earlier); blocks[nbGemm..) =
// scat: inline LDS scan of the (<=256) chunk sums; per-bucket bases into
// LDS; per-edge rank via LDS atomic; packed records bucket-contiguous.
// GEMM writes bufA, scat writes recs(=bufB)+bstart — fully disjoint.
__global__ __launch_bounds__(256) void k_scat_gemm(const int* __restrict__ ei,
                                                   const float* __restrict__ ew,
                                                   const int* __restrict__ pre,
                                                   const int* __restrict__ bsumRaw,
                                                   int* __restrict__ bucketStart,
                                                   int2* __restrict__ recs,
                                                   int E, int nbkt, int nbCount,
                                                   int nbScan,
                                                   const float* __restrict__ x,
                                                   const ushort* __restrict__ WbT,
                                                   unsigned* __restrict__ O, int M,
                                                   int nbGemm) {
    __shared__ unsigned sBuf[8192];            // 32 KB (gemm epilogue / scat)
    if (blockIdx.x < nbGemm) {
        gemm_tile<true>(x, WbT, O, M, blockIdx.x, sBuf);
        return;
    }
    // carve scat's LDS from sBuf (2084 u32 used)
    int* sRaw = (int*)sBuf;                    // 256
    int* sPre = sRaw + 256;                    // 256
    int* sWt  = sPre + 256;                    // 4
    int* sBase = sWt + 4;                      // 784
    unsigned* rk = (unsigned*)(sBase + 784);   // 784
    int t = threadIdx.x;
    sRaw[t] = (t < nbScan) ? bsumRaw[t] : 0;
    for (int b = t; b < nbkt; b += 256) rk[b] = 0;
    __syncthreads();
    int lane = t & 63, w2 = t >> 6;
    int v = sRaw[t];
    int xv = v;
#pragma unroll
    for (int off = 1; off < 64; off <<= 1) {
        int y = __shfl_up(xv, off, 64);
        if (lane >= off) xv += y;
    }
    if (lane == 63) sWt[w2] = xv;
    __syncthreads();
    int base = 0;
#pragma unroll
    for (int q = 0; q < 4; q++) { if (q < w2) base += sWt[q]; }
    sPre[t] = base + xv - v;                   // exclusive prefix of chunk sums
    __syncthreads();
    int blk = blockIdx.x - nbGemm;
    for (int b = t; b < nbkt; b += 256) {
        int f = b * nbCount + blk;
        sBase[b] = pre[f] + sPre[f >> 10];     // this block's base in bucket b
    }
    if (blk == 0) {
        for (int b = t; b <= nbkt; b += 256) {
            if (b == nbkt) bucketStart[b] = E;
            else { int f = b * nbCount; bucketStart[b] = pre[f] + sPre[f >> 10]; }
        }
    }
    __syncthreads();
    int e0 = blk * 8192;
    for (int i = t; i < 8192; i += 256) {
        int e = e0 + i;
        if (e < E) {
            int r = ei[e];
            int c = ei[E + e];
            float w = ew[e];
            int b = (unsigned)c >> 7;
            unsigned rank = atomicAdd(&rk[b], 1u);      // LDS atomic
            int2 rec; rec.x = r | ((c & 127) << 17); rec.y = __float_as_int(w);
            recs[sBase[b] + (int)rank] = rec;
        }
    }
}

// Pass D: one block per bucket (128 nodes). Count + weighted degree in LDS;
// dinv = rsqrt(1 + wdeg); SELF-LOOP edge at each node's list head
// (y = dinv[c]; k_agg L1's *dinv[src] makes it dinv^2); ptr includes the
// self slot; in-bucket scatter with csr.y = w * dinv[c]. csr.x is stored
// PRE-SCALED as node*16 (uint4-row index) for k_agg's addressing.
__global__ __launch_bounds__(256) void k_fin(const int2* __restrict__ recs,
                                             const int* __restrict__ bucketStart,
                                             int2* __restrict__ csr,
                                             int* __restrict__ ptrv,
                                             float* __restrict__ dinv,
                                             int N, int nbkt) {
    __shared__ unsigned scnt[128];
    __shared__ float swdeg[128];
    __shared__ float sdinv[128];
    __shared__ unsigned sTot0;
    int t = threadIdx.x;
    int b = blockIdx.x;
    int e0 = bucketStart[b], e1 = bucketStart[b + 1];
    int FB = e0 + b * 128;                     // final base incl. prior selfs
    if (t < 128) { scnt[t] = 0u; swdeg[t] = 0.f; }
    __syncthreads();
    for (int i = e0 + t; i < e1; i += 256) {
        int2 rec = recs[i];
        int cl = (rec.x >> 17) & 127;
        atomicAdd(&scnt[cl], 1u);                       // LDS atomic
        atomicAdd(&swdeg[cl], __int_as_float(rec.y));   // LDS f32 atomic
    }
    __syncthreads();
    unsigned myc = (t < 128) ? scnt[t] : 0u;
    int lane = t & 63, wv = t >> 6;
    unsigned inc = myc;
#pragma unroll
    for (int off = 1; off < 64; off <<= 1) {
        unsigned y = __shfl_up(inc, off, 64);
        if (lane >= off) inc += y;
    }
    if (t == 63) sTot0 = inc;                  // wave-0 total
    __syncthreads();
    unsigned excl = inc - myc + ((wv == 1) ? sTot0 : 0u);
    if (t < 128) {
        float dv = rsqrtf(1.0f + swdeg[t]);
        sdinv[t] = dv;
        scnt[t] = excl + (unsigned)t + 1u;     // scatter cursor (rel. to FB)
        int node = b * 128 + t;
        int start = FB + (int)excl + t;
        if (node < N) {
            ptrv[node] = start;
            dinv[node] = dv;
            int2 sv; sv.x = node << 4;         // self: w=1*dinv[c], scaled idx
            sv.y = __float_as_int(dv);
            csr[start] = sv;
        }
    }
    if (b == nbkt - 1 && t == 0) ptrv[N] = e1 + N;  // = E + N
    __syncthreads();
    for (int i = e0 + t; i < e1; i += 256) {
        int2 rec = recs[i];
        int cl = (rec.x >> 17) & 127;
        int r = rec.x & 131071;
        unsigned rank = atomicAdd(&scnt[cl], 1u);       // LDS atomic
        float y = __int_as_float(rec.y) * sdinv[cl];
        int2 mv; mv.x = r << 4; mv.y = __float_as_int(y);
        csr[FB + (int)rank] = mv;
    }
}

// One wave per node, uniform edge list (self-loop is edge 0). QUAD-EDGE
// uint4 gather (R16, best measured): lane = (grp = lane>>4 in 0..3,
// q = lane&15). One wave-level load covers 4 edges x 16B/lane; each lane
// accumulates 8 features (8q..8q+7). csr.x is the pre-scaled uint4-row
// index (node*16), so addr = m.x + q (one 32-bit add). NORM (layer 1):
// csr.y *= dinv[src] on first use, written back (entry owned by one wave).
template <bool NORM>
__global__ __launch_bounds__(256) void k_agg(const unsigned* __restrict__ HL,
                                             const int* __restrict__ ptr,
                                             int2* __restrict__ csr,
                                             const float* __restrict__ dinv,
                                             const float* __restrict__ bias,
                                             unsigned* __restrict__ Hout, int M) {
    __shared__ int2 sM[4 * 64];
    int node = (int)((blockIdx.x * blockDim.x + threadIdx.x) >> 6);
    if (node >= M) return;
    int lane = threadIdx.x & 63;
    int grp = lane >> 4;                  // edge subgroup 0..3
    int q = lane & 15;                    // features 8q .. 8q+7 (one uint4)
    int2* mbase = &sM[(threadIdx.x >> 6) * 64];
    int e0 = ptr[node], e1 = ptr[node + 1];
    int deg = e1 - e0;                    // includes self edge
    int nbv = deg < 64 ? deg : 64;
    if (lane < nbv) {
        int2 m = csr[e0 + lane];          // one coalesced load
        if (NORM) {
            m.y = __float_as_int(__int_as_float(m.y) * dinv[m.x >> 4]);
            csr[e0 + lane] = m;           // finalize for layers 2/3
        }
        mbase[lane] = m;
    }
    const uint4* HL4 = (const uint4*)HL;  // row = 16 uint4
    float a0 = 0.f, a1 = 0.f, a2 = 0.f, a3 = 0.f;
    float a4 = 0.f, a5 = 0.f, a6 = 0.f, a7 = 0.f;
    int j = grp;
    for (; j + 16 <= nbv; j += 16) {      // 4 quads (16 edges) in flight
        int2 m[4]; uint4 u[4];
#pragma unroll
        for (int t = 0; t < 4; t++) m[t] = mbase[j + 4 * t];
#pragma unroll
        for (int t = 0; t < 4; t++) u[t] = HL4[(unsigned)(m[t].x + q)];
#pragma unroll
        for (int t = 0; t < 4; t++) {
            float nv = __int_as_float(m[t].y);
            a0 += nv * bf_lo(u[t].x); a1 += nv * bf_hi(u[t].x);
            a2 += nv * bf_lo(u[t].y); a3 += nv * bf_hi(u[t].y);
            a4 += nv * bf_lo(u[t].z); a5 += nv * bf_hi(u[t].z);
            a6 += nv * bf_lo(u[t].w); a7 += nv * bf_hi(u[t].w);
        }
    }
    for (; j < nbv; j += 4) {             // remainder quads
        int2 m = mbase[j];
        uint4 u = HL4[(unsigned)(m.x + q)];
        float nv = __int_as_float(m.y);
        a0 += nv * bf_lo(u.x); a1 += nv * bf_hi(u.x);
        a2 += nv * bf_lo(u.y); a3 += nv * bf_hi(u.y);
        a4 += nv * bf_lo(u.z); a5 += nv * bf_hi(u.z);
        a6 += nv * bf_lo(u.w); a7 += nv * bf_hi(u.w);
    }
    for (int e = e0 + 64 + grp; e < e1; e += 4) {  // rare high-degree tail
        int2 m = csr[e];
        if (NORM) {
            m.y = __float_as_int(__int_as_float(m.y) * dinv[m.x >> 4]);
            csr[e] = m;
        }
        uint4 u = HL4[(unsigned)(m.x + q)];
        float nv = __int_as_float(m.y);
        a0 += nv * bf_lo(u.x); a1 += nv * bf_hi(u.x);
        a2 += nv * bf_lo(u.y); a3 += nv * bf_hi(u.y);
        a4 += nv * bf_lo(u.z); a5 += nv * bf_hi(u.z);
        a6 += nv * bf_lo(u.w); a7 += nv * bf_hi(u.w);
    }
    // combine the 4 edge subgroups (grp 0<->2,1<->3 then 0<->1,2<->3)
    a0 += __shfl_xor(a0, 32, 64); a1 += __shfl_xor(a1, 32, 64);
    a2 += __shfl_xor(a2, 32, 64); a3 += __shfl_xor(a3, 32, 64);
    a4 += __shfl_xor(a4, 32, 64); a5 += __shfl_xor(a5, 32, 64);
    a6 += __shfl_xor(a6, 32, 64); a7 += __shfl_xor(a7, 32, 64);
    a0 += __shfl_xor(a0, 16, 64); a1 += __shfl_xor(a1, 16, 64);
    a2 += __shfl_xor(a2, 16, 64); a3 += __shfl_xor(a3, 16, 64);
    a4 += __shfl_xor(a4, 16, 64); a5 += __shfl_xor(a5, 16, 64);
    a6 += __shfl_xor(a6, 16, 64); a7 += __shfl_xor(a7, 16, 64);
    if (grp == 0) {
        const float4* b4 = (const float4*)bias;
        float4 bA = b4[2 * q], bB = b4[2 * q + 1];
        float r0 = fmaxf(a0 + bA.x, 0.f);
        float r1 = fmaxf(a1 + bA.y, 0.f);
        float r2 = fmaxf(a2 + bA.z, 0.f);
        float r3 = fmaxf(a3 + bA.w, 0.f);
        float r4 = fmaxf(a4 + bB.x, 0.f);
        float r5 = fmaxf(a5 + bB.y, 0.f);
        float r6 = fmaxf(a6 + bB.z, 0.f);
        float r7 = fmaxf(a7 + bB.w, 0.f);
        uint4 pv;
        pv.x = pack_bf16x2(r0, r1);
        pv.y = pack_bf16x2(r2, r3);
        pv.z = pack_bf16x2(r4, r5);
        pv.w = pack_bf16x2(r6, r7);
        ((uint4*)(Hout + (size_t)node * 64))[q] = pv;
    }
}

// Heterogeneous: blocks[0..nbGemm) = next-layer GEMM reading Hb;
// blocks[nbGemm..nbGemm+G) = pool of the SAME Hb into outp (both depend only
// on the preceding agg). nbGemm=0 -> pool-only (final layer).
__global__ __launch_bounds__(256) void k_gemm_pool(const unsigned* __restrict__ Hb,
                                                   const ushort* __restrict__ WbT,
                                                   unsigned* __restrict__ O, int M,
                                                   const int* __restrict__ gb,
                                                   float* __restrict__ outp,
                                                   int nbGemm) {
    __shared__ unsigned sBuf[8192];            // gemm epilogue / pool partials
    if (blockIdx.x < nbGemm) {
        gemm_tile<false>(Hb, WbT, O, M, blockIdx.x, sBuf);
        return;
    }
    pool_tile(Hb, gb, outp, blockIdx.x - nbGemm, (float*)sBuf);
}

extern "C" void kernel_launch(void* const* d_in, const int* in_sizes, int n_in,
                              void* d_out, int out_size, void* d_ws, size_t ws_size,
                              hipStream_t stream) {
    const float* x     = (const float*)d_in[0];
    const int*   ei    = (const int*)d_in[1];
    const float* ew    = (const float*)d_in[2];
    const int*   batch = (const int*)d_in[3];
    const float* Wt[3] = {(const float*)d_in[4], (const float*)d_in[6], (const float*)d_in[8]};
    const float* bt[3] = {(const float*)d_in[5], (const float*)d_in[7], (const float*)d_in[9]};
    float* out = (float*)d_out;

    const int D = 128;
    const int N = in_sizes[0] / D;       // 100000
    const int E = in_sizes[2];           // 1600000
    const int G = out_size / (3 * D);    // 256

    // workspace carve-up (256 B aligned)
    char* p = (char*)d_ws;
    auto alloc = [&](size_t bytes) {
        void* r = (void*)p;
        p += (bytes + 255) & ~(size_t)255;
        return r;
    };
    int nbkt    = (N + 127) / 128;              // 782 coarse buckets (== nbGemm)
    int nbCount = (E + 8191) / 8192;            // 196 histogram blocks
    int F       = nbkt * nbCount;               // 153272 scan elements
    int nbScan  = (F + 1023) / 1024;            // 150 (<=256 for inline scan)

    int*      ptr    = (int*)alloc((size_t)(N + 1) * 4);
    int*      bsum   = (int*)alloc((size_t)256 * 4);
    int*      gb     = (int*)alloc((size_t)(G + 1) * 4);
    int*      bstart = (int*)alloc((size_t)(nbkt + 1) * 4);
    float*    dinv   = (float*)alloc((size_t)N * 4);
    ushort*   WbT    = (ushort*)alloc((size_t)3 * 16384 * 2);
    int2*     csr    = (int2*)alloc((size_t)(E + N) * 8);     // incl. selfs
    unsigned* bufA   = (unsigned*)alloc((size_t)N * 64 * 4);  // hl ping
    unsigned* bufB   = (unsigned*)alloc((size_t)N * 64 * 4);  // h / hl pong
    // aliases: hist+pre live only before k_fin writes csr; recs dead before
    // k_agg L1 writes bufB.
    int*  hist = (int*)csr;                    // F ints (613 KB)
    int*  pre  = hist + F;                     // F ints
    int2* recs = (int2*)bufB;                  // E int2 (12.8 MB)

    int nbGemm = nbkt;                          // 782 gemm blocks
    int nbPrep = (3 * 16384 + 255) / 256;       // 192 prep blocks (covers gb)

    // hist + prep (WbT x3, gb) — prep outputs consumed only by later dispatches
    k_hist_prep<<<nbCount + nbPrep, 256, 0, stream>>>(ei, hist, E, nbkt, nbCount,
                                                      batch, gb, G, N,
                                                      Wt[0], Wt[1], Wt[2], WbT);
    k_scan1<<<nbScan, 1024, 0, stream>>>(hist, pre, bsum, F);
    // layer-1 GEMM overlapped with the scatter pass (disjoint in/out)
    k_scat_gemm<<<nbGemm + nbCount, 256, 0, stream>>>(ei, ew, pre, bsum, bstart,
                                                      recs, E, nbkt, nbCount,
                                                      nbScan, x, WbT, bufA, N,
                                                      nbGemm);
    k_fin<<<nbkt, 256, 0, stream>>>(recs, bstart, csr, ptr, dinv, N, nbkt);

    // L1 aggregate (finalizes csr.y *= dinv[src] in-flight), then fused
    // (gemm_{l+1} + pool_l), final pool-only.
    k_agg<true><<<(N + 3) / 4, 256, 0, stream>>>(bufA, ptr, csr, dinv, bt[0],
                                                 bufB, N);
    k_gemm_pool<<<nbGemm + G, 256, 0, stream>>>(bufB, WbT + 16384, bufA, N,
                                                gb, out + 0 * (size_t)G * D, nbGemm);
    k_agg<false><<<(N + 3) / 4, 256, 0, stream>>>(bufA, ptr, csr, dinv, bt[1],
                                                  bufB, N);
    k_gemm_pool<<<nbGemm + G, 256, 0, stream>>>(bufB, WbT + 2 * 16384, bufA, N,
                                                gb, out + 1 * (size_t)G * D, nbGemm);
    k_agg<false><<<(N + 3) / 4, 256, 0, stream>>>(bufA, ptr, csr, dinv, bt[2],
                                                  bufB, N);
    k_gemm_pool<<<G, 256, 0, stream>>>(bufB, WbT, nullptr, 0,
                                       gb, out + 2 * (size_t)G * D, 0);
}

// Round 9
// 495.123 us; speedup vs baseline: 1.1986x; 1.0070x over previous
//
#include <hip/hip_runtime.h>

// ---------------------------------------------------------------------------
// GCN block: 3 x (GCNConv -> ReLU -> global_mean_pool)
// 10 dispatches. ZERO device-scope atomics in the CSR build (R11: 1.6M
// device atomics rate-limit ~18G/s memory-side regardless of structure).
// k_agg is at its structural roofline (R13/R16/R17: ~3.5TB/s L2-miss service
// on random 256B gathers; all levers neutral-or-negative) — R6 quad-edge
// form kept verbatim. R19 (this round): the scat phase was latency-bound at
// 3 waves/CU (R18: k_scat_gemm 74us, occupancy 11.7%, all pipes idle — the
// 196-block scat tail dominated). Re-parallelized 4x: nbCount 196->782
// (2048 edges/block for hist+scat); k_scan1 widened to 4096-element chunks
// (int4, 4 elems/thread) so the chunk-sum count stays <=256 for the inline
// scan (F = 782*782 = 611K, nbScan = 150).
//   k_hist_prep: blocks[0..782) = LDS histogram over 782 coarse buckets
//                (col>>7), 2048 edges/block, plain writes; blocks[782..974)
//                = WbT transpose/cast x3 + gb binary search (consumed only
//                in later dispatches).
//   k_scan1:     4096-chunk exclusive scan over the 611K hist matrix
//   k_scat_gemm: blocks[0..782) = layer-1 MFMA GEMM (fp32 x, in-reg bf16
//                cast; WbT1 ready since dispatch 1); blocks[782..1564) =
//                scat (inline LDS scan of 150 chunk sums; LDS-atomic ranks;
//                packed (r|c_local<<17, w) records bucket-contiguous,
//                recs=bufB). GEMM writes bufA; disjoint.
//   k_fin:       per bucket: count + weighted degree in LDS, dinv, ptr,
//                self-loop edge at list head, csr.x = node*16 (uint4-row
//                index), csr.y = w*dinv[c]
//   per layer:   k_agg<NORM> (wave-per-node quad-edge uint4 gather; NORM on
//                layer 1: csr.y *= dinv[src], written back, race-free) ->
//                k_gemm_pool (next-layer GEMM + prev-layer pool fused;
//                final call pool-only, nbGemm=0)
// hist/pre alias csr (dead before k_fin); recs aliases bufB (dead before
// k_agg L1 writes bufB).
// ---------------------------------------------------------------------------

typedef short short8 __attribute__((ext_vector_type(8)));   // 8 bf16 (4 VGPR)
typedef float f32x4  __attribute__((ext_vector_type(4)));   // MFMA C/D

__device__ inline unsigned pack_bf16x2(float a, float b) {
    unsigned ua = __float_as_uint(a);
    ua = (ua + 0x7FFFu + ((ua >> 16) & 1u)) >> 16;       // RNE
    unsigned ub = __float_as_uint(b);
    ub = (ub + 0x7FFFu + ((ub >> 16) & 1u)) >> 16;
    return ua | (ub << 16);
}
__device__ inline ushort bf16_1(float a) {
    unsigned ua = __float_as_uint(a);
    return (ushort)((ua + 0x7FFFu + ((ua >> 16) & 1u)) >> 16);
}
__device__ inline float bf_lo(unsigned u) { return __uint_as_float(u << 16); }
__device__ inline float bf_hi(unsigned u) { return __uint_as_float(u & 0xFFFF0000u); }

// ---- shared device bodies -------------------------------------------------

// One block = 128 rows x 128 cols of hl = H @ W (v_mfma_f32_16x16x32_bf16).
// Wave = 32 rows: 2 m-strips x 8 n-tiles, 64 MFMAs. A-frag 16B/lane
// contiguous (F32IN: 32B fp32 -> in-register bf16 cast). B from WbT[n][k].
// Epilogue via LDS (sOut, 8192 u32) -> coalesced u32 stores.
template <bool F32IN>
__device__ __forceinline__ void gemm_tile(const void* __restrict__ Hin,
                                          const ushort* __restrict__ WbT,
                                          unsigned* __restrict__ O, int M,
                                          int bid, unsigned* sOut) {
    int lane = threadIdx.x & 63;
    int wv = threadIdx.x >> 6;
    int quad = lane >> 4;
    int mrow = lane & 15;
    int m0 = bid * 128 + wv * 32;
    int r0 = m0 + mrow;
    int r1 = r0 + 16;
    int r0c = r0 < M ? r0 : M - 1;             // clamp loads, guard stores
    int r1c = r1 < M ? r1 : M - 1;

    short8 a0[4], a1[4];
    if (F32IN) {
        const float* Hf = (const float*)Hin;
#pragma unroll
        for (int s = 0; s < 4; s++) {          // k-step s covers k in [32s,32s+32)
            const float4* p0 = (const float4*)(Hf + (size_t)r0c * 128 + s * 32 + quad * 8);
            const float4* p1 = (const float4*)(Hf + (size_t)r1c * 128 + s * 32 + quad * 8);
            float4 f0 = p0[0], f1 = p0[1];
            float4 g0 = p1[0], g1 = p1[1];
            union { short8 s8; unsigned u[4]; } t0, t1;
            t0.u[0] = pack_bf16x2(f0.x, f0.y); t0.u[1] = pack_bf16x2(f0.z, f0.w);
            t0.u[2] = pack_bf16x2(f1.x, f1.y); t0.u[3] = pack_bf16x2(f1.z, f1.w);
            t1.u[0] = pack_bf16x2(g0.x, g0.y); t1.u[1] = pack_bf16x2(g0.z, g0.w);
            t1.u[2] = pack_bf16x2(g1.x, g1.y); t1.u[3] = pack_bf16x2(g1.z, g1.w);
            a0[s] = t0.s8; a1[s] = t1.s8;
        }
    } else {
        const unsigned* Hb = (const unsigned*)Hin;
#pragma unroll
        for (int s = 0; s < 4; s++) {
            a0[s] = *(const short8*)(Hb + (size_t)r0c * 64 + s * 16 + quad * 4);
            a1[s] = *(const short8*)(Hb + (size_t)r1c * 64 + s * 16 + quad * 4);
        }
    }
    f32x4 acc0[8], acc1[8];
#pragma unroll
    for (int t = 0; t < 8; t++) {
        acc0[t] = (f32x4){0.f, 0.f, 0.f, 0.f};
        acc1[t] = (f32x4){0.f, 0.f, 0.f, 0.f};
    }
#pragma unroll
    for (int s = 0; s < 4; s++) {
#pragma unroll
        for (int t = 0; t < 8; t++) {
            short8 b = *(const short8*)(WbT + (t * 16 + mrow) * 128 + s * 32 + quad * 8);
            acc0[t] = __builtin_amdgcn_mfma_f32_16x16x32_bf16(a0[s], b, acc0[t], 0, 0, 0);
            acc1[t] = __builtin_amdgcn_mfma_f32_16x16x32_bf16(a1[s], b, acc1[t], 0, 0, 0);
        }
    }
    // C/D layout: col = lane&15, row = quad*4 + reg.
    ushort* so = (ushort*)(sOut + wv * 32 * 64);
#pragma unroll
    for (int t = 0; t < 8; t++) {
#pragma unroll
        for (int r = 0; r < 4; r++) {
            int lr = quad * 4 + r;
            int c = t * 16 + mrow;
            so[lr * 128 + c] = bf16_1(acc0[t][r]);
            so[(lr + 16) * 128 + c] = bf16_1(acc1[t][r]);
        }
    }
    __syncthreads();
    const unsigned* si = sOut + wv * 32 * 64;
#pragma unroll 8
    for (int r = 0; r < 32; r++) {
        int row = m0 + r;
        if (row < M) O[(size_t)row * 64 + lane] = si[r * 64 + lane];
    }
}

// One block per graph: stream the sorted node segment, 4 waves stride it,
// LDS-combine (part = 512 floats), divide by count, write. No atomics.
__device__ __forceinline__ void pool_tile(const unsigned* __restrict__ HB,
                                          const int* __restrict__ gb,
                                          float* __restrict__ outp, int g,
                                          float* part) {
    int lane = threadIdx.x & 63, w = threadIdx.x >> 6;
    int s = gb[g], e = gb[g + 1];
    float ax = 0.f, ay = 0.f;
    for (int i = s + w; i < e; i += 4) {
        unsigned u = HB[(size_t)i * 64 + lane];
        ax += bf_lo(u); ay += bf_hi(u);
    }
    part[w * 128 + lane * 2] = ax;
    part[w * 128 + lane * 2 + 1] = ay;
    __syncthreads();
    if (threadIdx.x < 128) {
        float sum = part[threadIdx.x] + part[128 + threadIdx.x]
                  + part[256 + threadIdx.x] + part[384 + threadIdx.x];
        float c = (float)(e - s);
        outp[g * 128 + threadIdx.x] = sum / fmaxf(c, 1.0f);
    }
}

// ---- kernels --------------------------------------------------------------

// Heterogeneous: blocks[0..nbCount) = LDS histogram over nbkt coarse buckets
// (col>>7), 2048 edges/block, plain hist writes; blocks[nbCount..) = prep
// work (WbT transpose/cast x3 + gb binary search) consumed only by LATER
// dispatches (scat_gemm / gemm_pool) — no same-dispatch ordering needed.
__global__ __launch_bounds__(256) void k_hist_prep(const int* __restrict__ ei,
                                                   int* __restrict__ hist, int E,
                                                   int nbkt, int nbCount,
                                                   const int* __restrict__ batch,
                                                   int* __restrict__ gb, int G, int N,
                                                   const float* __restrict__ W0,
                                                   const float* __restrict__ W1,
                                                   const float* __restrict__ W2,
                                                   ushort* __restrict__ WbT) {
    __shared__ unsigned hcnt[1024];            // 4 KB (hist counters, nbkt<=1024)
    int t = threadIdx.x;
    if (blockIdx.x >= nbCount) {               // prep blocks
        int id = (blockIdx.x - nbCount) * 256 + t;
        if (id <= G) {
            int lo = 0, hi = N;
            while (lo < hi) { int mid = (lo + hi) >> 1; if (batch[mid] < id) lo = mid + 1; else hi = mid; }
            gb[id] = lo;
        }
        if (id < 3 * 16384) {
            int l = id >> 14;
            const float* W = (l == 0) ? W0 : ((l == 1) ? W1 : W2);
            int id2 = id & 16383;
            int n = id2 & 127, k = id2 >> 7;
            WbT[l * 16384 + n * 128 + k] = bf16_1(W[k * 128 + n]);
        }
        return;
    }
    int blk = blockIdx.x;
    for (int i = t; i < nbkt; i += 256) hcnt[i] = 0;
    __syncthreads();
    int base = blk * 2048;
    for (int i = t; i < 2048; i += 256) {
        int e = base + i;
        if (e < E) atomicAdd(&hcnt[(unsigned)ei[E + e] >> 7], 1u);  // LDS atomic
    }
    __syncthreads();
    for (int b = t; b < nbkt; b += 256)        // bucket-major layout
        hist[b * nbCount + blk] = (int)hcnt[b];
}

// 4096-chunk exclusive scan (4 elems/thread via int4): pre[i] = chunk-local
// exclusive prefix, bsum[chunk] = chunk total. n = nbkt*nbCount (~611K),
// nbScan = ceil(n/4096) = 150 <= 256 for the downstream inline scan.
__global__ __launch_bounds__(1024) void k_scan1(const int* __restrict__ cnt,
                                                int* __restrict__ pre,
                                                int* __restrict__ bsum, int n) {
    __shared__ int wsum[16];
    int t = threadIdx.x, lane = t & 63, w = t >> 6;
    int i0 = blockIdx.x * 4096 + t * 4;
    int c0 = 0, c1 = 0, c2 = 0, c3 = 0;
    if (i0 + 3 < n) {
        int4 v4 = *(const int4*)(cnt + i0);
        c0 = v4.x; c1 = v4.y; c2 = v4.z; c3 = v4.w;
    } else {
        if (i0 < n)     c0 = cnt[i0];
        if (i0 + 1 < n) c1 = cnt[i0 + 1];
        if (i0 + 2 < n) c2 = cnt[i0 + 2];
        if (i0 + 3 < n) c3 = cnt[i0 + 3];
    }
    int v = c0 + c1 + c2 + c3;                 // thread total
    int x = v;
#pragma unroll
    for (int off = 1; off < 64; off <<= 1) {
        int y = __shfl_up(x, off, 64);
        if (lane >= off) x += y;
    }
    if (lane == 63) wsum[w] = x;
    __syncthreads();
    int woff = 0, tot = 0;
#pragma unroll
    for (int q = 0; q < 16; q++) { int s = wsum[q]; if (q < w) woff += s; tot += s; }
    int base = woff + x - v;                   // thread-exclusive base
    if (i0 + 3 < n) {
        int4 o; o.x = base; o.y = base + c0; o.z = base + c0 + c1;
        o.w = base + c0 + c1 + c2;
        *(int4*)(pre + i0) = o;
    } else {
        if (i0 < n)     pre[i0]     = base;
        if (i0 + 1 < n) pre[i0 + 1] = base + c0;
        if (i0 + 2 < n) pre[i0 + 2] = base + c0 + c1;
        if (i0 + 3 < n) pre[i0 + 3] = base + c0 + c1 + c2;
    }
    if (t == 0) bsum[blockIdx.x] = tot;
}

// Heterogeneous: blocks[0..nbGemm) = layer-1 GEMM (fp32 x, in-reg bf16 cast;
// WbT1 produced by k_hist_prep); blocks[nbGemm..nbGemm+nbCount) = scat:
// inline LDS scan of the (<=256) chunk sums; per-bucket bases into LDS;
// per-edge rank via LDS atomic; packed records bucket-contiguous. 2048
// edges/scat-block (R19: 782 scat blocks = 20 waves/CU during the tail vs
// R18's 3 — the scat phase was occupancy-starved).
__global__ __launch_bounds__(256) void k_scat_gemm(const int* __restrict__ ei,
                                                   const float* __restrict__ ew,
                                                   const int* __restrict__ pre,
                                                   const int* __restrict__ bsumRaw,
                                                   int* __restrict__ bucketStart,
                                                   int2* __restrict__ recs,
                                                   int E, int nbkt, int nbCount,
                                                   int nbScan,
                                                   const float* __restrict__ x,
                                                   const ushort* __restrict__ WbT,
                                                   unsigned* __restrict__ O, int M,
                                                   int nbGemm) {
    __shared__ unsigned sBuf[8192];            // 32 KB (gemm epilogue / scat)
    if (blockIdx.x < nbGemm) {
        gemm_tile<true>(x, WbT, O, M, blockIdx.x, sBuf);
        return;
    }
    // carve scat's LDS from sBuf (2084 u32 used)
    int* sRaw = (int*)sBuf;                    // 256
    int* sPre = sRaw + 256;                    // 256
    int* sWt  = sPre + 256;                    // 4
    int* sBase = sWt + 4;                      // 784
    unsigned* rk = (unsigned*)(sBase + 784);   // 784
    int t = threadIdx.x;
    sRaw[t] = (t < nbScan) ? bsumRaw[t] : 0;
    for (int b = t; b < nbkt; b += 256) rk[b] = 0;
    __syncthreads();
    int lane = t & 63, w2 = t >> 6;
    int v = sRaw[t];
    int xv = v;
#pragma unroll
    for (int off = 1; off < 64; off <<= 1) {
        int y = __shfl_up(xv, off, 64);
        if (lane >= off) xv += y;
    }
    if (lane == 63) sWt[w2] = xv;
    __syncthreads();
    int base = 0;
#pragma unroll
    for (int q = 0; q < 4; q++) { if (q < w2) base += sWt[q]; }
    sPre[t] = base + xv - v;                   // exclusive prefix of chunk sums
    __syncthreads();
    int blk = blockIdx.x - nbGemm;
    for (int b = t; b < nbkt; b += 256) {
        int f = b * nbCount + blk;
        sBase[b] = pre[f] + sPre[f >> 12];     // this block's base in bucket b
    }
    if (blk == 0) {
        for (int b = t; b <= nbkt; b += 256) {
            if (b == nbkt) bucketStart[b] = E;
            else { int f = b * nbCount; bucketStart[b] = pre[f] + sPre[f >> 12]; }
        }
    }
    __syncthreads();
    int e0 = blk * 2048;
    for (int i = t; i < 2048; i += 256) {
        int e = e0 + i;
        if (e < E) {
            int r = ei[e];
            int c = ei[E + e];
            float w = ew[e];
            int b = (unsigned)c >> 7;
            unsigned rank = atomicAdd(&rk[b], 1u);      // LDS atomic
            int2 rec; rec.x = r | ((c & 127) << 17); rec.y = __float_as_int(w);
            recs[sBase[b] + (int)rank] = rec;
        }
    }
}

// Pass D: one block per bucket (128 nodes). Count + weighted degree in LDS;
// dinv = rsqrt(1 + wdeg); SELF-LOOP edge at each node's list head
// (y = dinv[c]; k_agg L1's *dinv[src] makes it dinv^2); ptr includes the
// self slot; in-bucket scatter with csr.y = w * dinv[c]. csr.x is stored
// PRE-SCALED as node*16 (uint4-row index) for k_agg's addressing.
__global__ __launch_bounds__(256) void k_fin(const int2* __restrict__ recs,
                                             const int* __restrict__ bucketStart,
                                             int2* __restrict__ csr,
                                             int* __restrict__ ptrv,
                                             float* __restrict__ dinv,
                                             int N, int nbkt) {
    __shared__ unsigned scnt[128];
    __shared__ float swdeg[128];
    __shared__ float sdinv[128];
    __shared__ unsigned sTot0;
    int t = threadIdx.x;
    int b = blockIdx.x;
    int e0 = bucketStart[b], e1 = bucketStart[b + 1];
    int FB = e0 + b * 128;                     // final base incl. prior selfs
    if (t < 128) { scnt[t] = 0u; swdeg[t] = 0.f; }
    __syncthreads();
    for (int i = e0 + t; i < e1; i += 256) {
        int2 rec = recs[i];
        int cl = (rec.x >> 17) & 127;
        atomicAdd(&scnt[cl], 1u);                       // LDS atomic
        atomicAdd(&swdeg[cl], __int_as_float(rec.y));   // LDS f32 atomic
    }
    __syncthreads();
    unsigned myc = (t < 128) ? scnt[t] : 0u;
    int lane = t & 63, wv = t >> 6;
    unsigned inc = myc;
#pragma unroll
    for (int off = 1; off < 64; off <<= 1) {
        unsigned y = __shfl_up(inc, off, 64);
        if (lane >= off) inc += y;
    }
    if (t == 63) sTot0 = inc;                  // wave-0 total
    __syncthreads();
    unsigned excl = inc - myc + ((wv == 1) ? sTot0 : 0u);
    if (t < 128) {
        float dv = rsqrtf(1.0f + swdeg[t]);
        sdinv[t] = dv;
        scnt[t] = excl + (unsigned)t + 1u;     // scatter cursor (rel. to FB)
        int node = b * 128 + t;
        int start = FB + (int)excl + t;
        if (node < N) {
            ptrv[node] = start;
            dinv[node] = dv;
            int2 sv; sv.x = node << 4;         // self: w=1*dinv[c], scaled idx
            sv.y = __float_as_int(dv);
            csr[start] = sv;
        }
    }
    if (b == nbkt - 1 && t == 0) ptrv[N] = e1 + N;  // = E + N
    __syncthreads();
    for (int i = e0 + t; i < e1; i += 256) {
        int2 rec = recs[i];
        int cl = (rec.x >> 17) & 127;
        int r = rec.x & 131071;
        unsigned rank = atomicAdd(&scnt[cl], 1u);       // LDS atomic
        float y = __int_as_float(rec.y) * sdinv[cl];
        int2 mv; mv.x = r << 4; mv.y = __float_as_int(y);
        csr[FB + (int)rank] = mv;
    }
}

// One wave per node, uniform edge list (self-loop is edge 0). QUAD-EDGE
// uint4 gather (R16, best measured): lane = (grp = lane>>4 in 0..3,
// q = lane&15). One wave-level load covers 4 edges x 16B/lane; each lane
// accumulates 8 features (8q..8q+7). csr.x is the pre-scaled uint4-row
// index (node*16), so addr = m.x + q (one 32-bit add). NORM (layer 1):
// csr.y *= dinv[src] on first use, written back (entry owned by one wave).
template <bool NORM>
__global__ __launch_bounds__(256) void k_agg(const unsigned* __restrict__ HL,
                                             const int* __restrict__ ptr,
                                             int2* __restrict__ csr,
                                             const float* __restrict__ dinv,
                                             const float* __restrict__ bias,
                                             unsigned* __restrict__ Hout, int M) {
    __shared__ int2 sM[4 * 64];
    int node = (int)((blockIdx.x * blockDim.x + threadIdx.x) >> 6);
    if (node >= M) return;
    int lane = threadIdx.x & 63;
    int grp = lane >> 4;                  // edge subgroup 0..3
    int q = lane & 15;                    // features 8q .. 8q+7 (one uint4)
    int2* mbase = &sM[(threadIdx.x >> 6) * 64];
    int e0 = ptr[node], e1 = ptr[node + 1];
    int deg = e1 - e0;                    // includes self edge
    int nbv = deg < 64 ? deg : 64;
    if (lane < nbv) {
        int2 m = csr[e0 + lane];          // one coalesced load
        if (NORM) {
            m.y = __float_as_int(__int_as_float(m.y) * dinv[m.x >> 4]);
            csr[e0 + lane] = m;           // finalize for layers 2/3
        }
        mbase[lane] = m;
    }
    const uint4* HL4 = (const uint4*)HL;  // row = 16 uint4
    float a0 = 0.f, a1 = 0.f, a2 = 0.f, a3 = 0.f;
    float a4 = 0.f, a5 = 0.f, a6 = 0.f, a7 = 0.f;
    int j = grp;
    for (; j + 16 <= nbv; j += 16) {      // 4 quads (16 edges) in flight
        int2 m[4]; uint4 u[4];
#pragma unroll
        for (int t = 0; t < 4; t++) m[t] = mbase[j + 4 * t];
#pragma unroll
        for (int t = 0; t < 4; t++) u[t] = HL4[(unsigned)(m[t].x + q)];
#pragma unroll
        for (int t = 0; t < 4; t++) {
            float nv = __int_as_float(m[t].y);
            a0 += nv * bf_lo(u[t].x); a1 += nv * bf_hi(u[t].x);
            a2 += nv * bf_lo(u[t].y); a3 += nv * bf_hi(u[t].y);
            a4 += nv * bf_lo(u[t].z); a5 += nv * bf_hi(u[t].z);
            a6 += nv * bf_lo(u[t].w); a7 += nv * bf_hi(u[t].w);
        }
    }
    for (; j < nbv; j += 4) {             // remainder quads
        int2 m = mbase[j];
        uint4 u = HL4[(unsigned)(m.x + q)];
        float nv = __int_as_float(m.y);
        a0 += nv * bf_lo(u.x); a1 += nv * bf_hi(u.x);
        a2 += nv * bf_lo(u.y); a3 += nv * bf_hi(u.y);
        a4 += nv * bf_lo(u.z); a5 += nv * bf_hi(u.z);
        a6 += nv * bf_lo(u.w); a7 += nv * bf_hi(u.w);
    }
    for (int e = e0 + 64 + grp; e < e1; e += 4) {  // rare high-degree tail
        int2 m = csr[e];
        if (NORM) {
            m.y = __float_as_int(__int_as_float(m.y) * dinv[m.x >> 4]);
            csr[e] = m;
        }
        uint4 u = HL4[(unsigned)(m.x + q)];
        float nv = __int_as_float(m.y);
        a0 += nv * bf_lo(u.x); a1 += nv * bf_hi(u.x);
        a2 += nv * bf_lo(u.y); a3 += nv * bf_hi(u.y);
        a4 += nv * bf_lo(u.z); a5 += nv * bf_hi(u.z);
        a6 += nv * bf_lo(u.w); a7 += nv * bf_hi(u.w);
    }
    // combine the 4 edge subgroups (grp 0<->2,1<->3 then 0<->1,2<->3)
    a0 += __shfl_xor(a0, 32, 64); a1 += __shfl_xor(a1, 32, 64);
    a2 += __shfl_xor(a2, 32, 64); a3 += __shfl_xor(a3, 32, 64);
    a4 += __shfl_xor(a4, 32, 64); a5 += __shfl_xor(a5, 32, 64);
    a6 += __shfl_xor(a6, 32, 64); a7 += __shfl_xor(a7, 32, 64);
    a0 += __shfl_xor(a0, 16, 64); a1 += __shfl_xor(a1, 16, 64);
    a2 += __shfl_xor(a2, 16, 64); a3 += __shfl_xor(a3, 16, 64);
    a4 += __shfl_xor(a4, 16, 64); a5 += __shfl_xor(a5, 16, 64);
    a6 += __shfl_xor(a6, 16, 64); a7 += __shfl_xor(a7, 16, 64);
    if (grp == 0) {
        const float4* b4 = (const float4*)bias;
        float4 bA = b4[2 * q], bB = b4[2 * q + 1];
        float r0 = fmaxf(a0 + bA.x, 0.f);
        float r1 = fmaxf(a1 + bA.y, 0.f);
        float r2 = fmaxf(a2 + bA.z, 0.f);
        float r3 = fmaxf(a3 + bA.w, 0.f);
        float r4 = fmaxf(a4 + bB.x, 0.f);
        float r5 = fmaxf(a5 + bB.y, 0.f);
        float r6 = fmaxf(a6 + bB.z, 0.f);
        float r7 = fmaxf(a7 + bB.w, 0.f);
        uint4 pv;
        pv.x = pack_bf16x2(r0, r1);
        pv.y = pack_bf16x2(r2, r3);
        pv.z = pack_bf16x2(r4, r5);
        pv.w = pack_bf16x2(r6, r7);
        ((uint4*)(Hout + (size_t)node * 64))[q] = pv;
    }
}

// Heterogeneous: blocks[0..nbGemm) = next-layer GEMM reading Hb;
// blocks[nbGemm..nbGemm+G) = pool of the SAME Hb into outp (both depend only
// on the preceding agg). nbGemm=0 -> pool-only (final layer).
__global__ __launch_bounds__(256) void k_gemm_pool(const unsigned* __restrict__ Hb,
                                                   const ushort* __restrict__ WbT,
                                                   unsigned* __restrict__ O, int M,
                                                   const int* __restrict__ gb,
                                                   float* __restrict__ outp,
                                                   int nbGemm) {
    __shared__ unsigned sBuf[8192];            // gemm epilogue / pool partials
    if (blockIdx.x < nbGemm) {
        gemm_tile<false>(Hb, WbT, O, M, blockIdx.x, sBuf);
        return;
    }
    pool_tile(Hb, gb, outp, blockIdx.x - nbGemm, (float*)sBuf);
}

extern "C" void kernel_launch(void* const* d_in, const int* in_sizes, int n_in,
                              void* d_out, int out_size, void* d_ws, size_t ws_size,
                              hipStream_t stream) {
    const float* x     = (const float*)d_in[0];
    const int*   ei    = (const int*)d_in[1];
    const float* ew    = (const float*)d_in[2];
    const int*   batch = (const int*)d_in[3];
    const float* Wt[3] = {(const float*)d_in[4], (const float*)d_in[6], (const float*)d_in[8]};
    const float* bt[3] = {(const float*)d_in[5], (const float*)d_in[7], (const float*)d_in[9]};
    float* out = (float*)d_out;

    const int D = 128;
    const int N = in_sizes[0] / D;       // 100000
    const int E = in_sizes[2];           // 1600000
    const int G = out_size / (3 * D);    // 256

    // workspace carve-up (256 B aligned)
    char* p = (char*)d_ws;
    auto alloc = [&](size_t bytes) {
        void* r = (void*)p;
        p += (bytes + 255) & ~(size_t)255;
        return r;
    };
    int nbkt    = (N + 127) / 128;              // 782 coarse buckets (== nbGemm)
    int nbCount = (E + 2047) / 2048;            // 782 hist/scat blocks (R19)
    int F       = nbkt * nbCount;               // 611524 scan elements
    int nbScan  = (F + 4095) / 4096;            // 150 (<=256 for inline scan)

    int*      ptr    = (int*)alloc((size_t)(N + 1) * 4);
    int*      bsum   = (int*)alloc((size_t)256 * 4);
    int*      gb     = (int*)alloc((size_t)(G + 1) * 4);
    int*      bstart = (int*)alloc((size_t)(nbkt + 1) * 4);
    float*    dinv   = (float*)alloc((size_t)N * 4);
    ushort*   WbT    = (ushort*)alloc((size_t)3 * 16384 * 2);
    int2*     csr    = (int2*)alloc((size_t)(E + N) * 8);     // incl. selfs
    unsigned* bufA   = (unsigned*)alloc((size_t)N * 64 * 4);  // hl ping
    unsigned* bufB   = (unsigned*)alloc((size_t)N * 64 * 4);  // h / hl pong
    // aliases: hist+pre live only before k_fin writes csr (2F ints = 4.9MB
    // <= csr's 13.6MB); recs dead before k_agg L1 writes bufB.
    int*  hist = (int*)csr;                    // F ints
    int*  pre  = hist + F;                     // F ints
    int2* recs = (int2*)bufB;                  // E int2 (12.8 MB)

    int nbGemm = nbkt;                          // 782 gemm blocks
    int nbPrep = (3 * 16384 + 255) / 256;       // 192 prep blocks (covers gb)

    // hist + prep (WbT x3, gb) — prep outputs consumed only by later dispatches
    k_hist_prep<<<nbCount + nbPrep, 256, 0, stream>>>(ei, hist, E, nbkt, nbCount,
                                                      batch, gb, G, N,
                                                      Wt[0], Wt[1], Wt[2], WbT);
    k_scan1<<<nbScan, 1024, 0, stream>>>(hist, pre, bsum, F);
    // layer-1 GEMM overlapped with the scatter pass (disjoint in/out)
    k_scat_gemm<<<nbGemm + nbCount, 256, 0, stream>>>(ei, ew, pre, bsum, bstart,
                                                      recs, E, nbkt, nbCount,
                                                      nbScan, x, WbT, bufA, N,
                                                      nbGemm);
    k_fin<<<nbkt, 256, 0, stream>>>(recs, bstart, csr, ptr, dinv, N, nbkt);

    // L1 aggregate (finalizes csr.y *= dinv[src] in-flight), then fused
    // (gemm_{l+1} + pool_l), final pool-only.
    k_agg<true><<<(N + 3) / 4, 256, 0, stream>>>(bufA, ptr, csr, dinv, bt[0],
                                                 bufB, N);
    k_gemm_pool<<<nbGemm + G, 256, 0, stream>>>(bufB, WbT + 16384, bufA, N,
                                                gb, out + 0 * (size_t)G * D, nbGemm);
    k_agg<false><<<(N + 3) / 4, 256, 0, stream>>>(bufA, ptr, csr, dinv, bt[1],
                                                  bufB, N);
    k_gemm_pool<<<nbGemm + G, 256, 0, stream>>>(bufB, WbT + 2 * 16384, bufA, N,
                                                gb, out + 1 * (size_t)G * D, nbGemm);
    k_agg<false><<<(N + 3) / 4, 256, 0, stream>>>(bufA, ptr, csr, dinv, bt[2],
                                                  bufB, N);
    k_gemm_pool<<<G, 256, 0, stream>>>(bufB, WbT, nullptr, 0,
                                       gb, out + 2 * (size_t)G * D, 0);
}